// Round 1
// baseline (78.489 us; speedup 1.0000x reference)
//
#include <hip/hip_runtime.h>
#include <math.h>

#define NCH 64

typedef __bf16 bf16x8 __attribute__((ext_vector_type(8)));
typedef float f32x4 __attribute__((ext_vector_type(4)));

__global__ void ab_zero(float* __restrict__ ws) {
    int i = blockIdx.x * blockDim.x + threadIdx.x;
    if (i < NCH * 10) ws[i] = 0.0f;
}

// Main: per 16-neighbor tile per wave:
//   h2 = h @ W.T via mfma_f32_16x16x32_bf16 (M=16 nbrs, N=64 ch, K=64)
//   epilogue: radial(n,r) * h2 * monomials -> D[k][10] per-lane accumulators
__global__ __launch_bounds__(256, 2) void ab_main(
    const float* __restrict__ h, const float* __restrict__ rp,
    const float* __restrict__ W, float* __restrict__ ws, int N)
{
    const int lane = threadIdx.x & 63;
    const int wid  = threadIdx.x >> 6;
    const int c = lane & 15;   // A row / C col (k within 16-tile)
    const int g = lane >> 4;   // k-slot group
    const int gwave = blockIdx.x * 4 + wid;
    const int nwave = gridDim.x * 4;

    // B fragments from W: B[j,k] = W[k][j]; lane: col c -> k_local, slots g*8+e -> j
    bf16x8 Bf[4][2];
#pragma unroll
    for (int t = 0; t < 4; ++t)
#pragma unroll
      for (int jb = 0; jb < 2; ++jb) {
        const float* wp = W + (t * 16 + c) * NCH + jb * 32 + g * 8;
        f32x4 w0 = *(const f32x4*)wp;
        f32x4 w1 = *(const f32x4*)(wp + 4);
#pragma unroll
        for (int e = 0; e < 4; ++e) { Bf[t][jb][e] = (__bf16)w0[e]; Bf[t][jb][4 + e] = (__bf16)w1[e]; }
      }

    float D[4][10];
#pragma unroll
    for (int t = 0; t < 4; ++t)
#pragma unroll
      for (int p = 0; p < 10; ++p) D[t][p] = 0.0f;

    const float C0 = 0.632455532033676f; // sqrt(2/5)
    const int numTiles = N >> 4;         // N % 16 == 0 for this problem

    for (int tile = gwave; tile < numTiles; tile += nwave) {
        const int base = tile << 4;

        // A fragments: lane row c -> neighbor base+c, slots g*8+e (+32*jb) -> j
        const float* hp = h + (size_t)(base + c) * NCH + g * 8;
        bf16x8 Af[2];
#pragma unroll
        for (int jb = 0; jb < 2; ++jb) {
            f32x4 a0 = *(const f32x4*)(hp + jb * 32);
            f32x4 a1 = *(const f32x4*)(hp + jb * 32 + 4);
#pragma unroll
            for (int e = 0; e < 4; ++e) { Af[jb][e] = (__bf16)a0[e]; Af[jb][4 + e] = (__bf16)a1[e]; }
        }

        f32x4 acc[4];
#pragma unroll
        for (int t = 0; t < 4; ++t) acc[t] = (f32x4){0.f, 0.f, 0.f, 0.f};
#pragma unroll
        for (int jb = 0; jb < 2; ++jb)
#pragma unroll
          for (int t = 0; t < 4; ++t)
            acc[t] = __builtin_amdgcn_mfma_f32_16x16x32_bf16(Af[jb], Bf[t][jb], acc[t], 0, 0, 0);

        // C layout: lane holds rows (neighbors) g*4+i, col k = 16*t + c
        const int a0i = base + g * 4;
        f32x4 px = *(const f32x4*)(rp + a0i);
        f32x4 py = *(const f32x4*)(rp + N + a0i);
        f32x4 pz = *(const f32x4*)(rp + 2 * N + a0i);

#pragma unroll
        for (int i = 0; i < 4; ++i) {
            float x = px[i], y = py[i], z = pz[i];
            float r2 = x * x + y * y + z * z;
            float inv = rsqrtf(r2);
            float nx = x * inv, ny = y * inv, nz = z * inv;
            float rev1 = (r2 * inv) * 0.1f;   // r/10 revolutions per unit n (n*pi*r/5 rad)
            float coef = C0 * inv;            // sqrt(2/5)/r
            float xx = nx * nx, xy = nx * ny, xz = nx * nz;
            float yy = ny * ny, yz = ny * nz, zz = nz * nz;
            float m[10] = { xx * nx, xx * ny, xx * nz, xy * ny, xy * nz,
                            xz * nz, yy * ny, yy * nz, yz * nz, zz * nz };
            float revn = (float)(c + 1) * rev1;
            float rev16 = 16.0f * rev1;
#pragma unroll
            for (int t = 0; t < 4; ++t) {
                float rv = revn - floorf(revn);
                float s = __builtin_amdgcn_sinf(rv);     // sin(2*pi*rv)
                float v = s * coef * acc[t][i];
#pragma unroll
                for (int p = 0; p < 10; ++p) D[t][p] = fmaf(v, m[p], D[t][p]);
                revn += rev16;
            }
        }
    }

    // wave reduce across the 4 groups (same k set, different neighbors)
#pragma unroll
    for (int t = 0; t < 4; ++t)
#pragma unroll
      for (int p = 0; p < 10; ++p) {
        float v = D[t][p];
        v += __shfl_xor(v, 16);
        v += __shfl_xor(v, 32);
        D[t][p] = v;
      }

    __shared__ float Ds[4][NCH * 10];
    if (lane < 16) {
#pragma unroll
        for (int t = 0; t < 4; ++t)
#pragma unroll
          for (int p = 0; p < 10; ++p)
            Ds[wid][(c + 16 * t) * 10 + p] = D[t][p];
    }
    __syncthreads();
    for (int idx = threadIdx.x; idx < NCH * 10; idx += blockDim.x) {
        float s = Ds[0][idx] + Ds[1][idx] + Ds[2][idx] + Ds[3][idx];
        atomicAdd(&ws[idx], s);
    }
}

// expand 10 symmetric monomials -> 27-entry (x,y,z) tensor per channel
__global__ void ab_expand(const float* __restrict__ ws, float* __restrict__ out) {
    const unsigned char tab[27] = { 0,1,2, 1,3,4, 2,4,5,
                                    1,3,4, 3,6,7, 4,7,8,
                                    2,4,5, 4,7,8, 5,8,9 };
    int i = blockIdx.x * blockDim.x + threadIdx.x;
    if (i < NCH * 27) {
        int k = i / 27, cc = i % 27;
        out[i] = ws[k * 10 + tab[cc]];
    }
}

extern "C" void kernel_launch(void* const* d_in, const int* in_sizes, int n_in,
                              void* d_out, int out_size, void* d_ws, size_t ws_size,
                              hipStream_t stream) {
    const float* h  = (const float*)d_in[0];
    const float* rp = (const float*)d_in[1];
    const float* W  = (const float*)d_in[2];
    float* out = (float*)d_out;
    float* ws  = (float*)d_ws;
    const int N = in_sizes[1] / 3;

    ab_zero<<<1, 640, 0, stream>>>(ws);
    ab_main<<<512, 256, 0, stream>>>(h, rp, W, ws, N);
    ab_expand<<<(NCH * 27 + 255) / 256, 256, 0, stream>>>(ws, out);
}

// Round 2
// 76.068 us; speedup vs baseline: 1.0318x; 1.0318x over previous
//
#include <hip/hip_runtime.h>
#include <math.h>

#define NCH 64

typedef __bf16 bf16x8 __attribute__((ext_vector_type(8)));
typedef float f32x4 __attribute__((ext_vector_type(4)));

__global__ void ab_zero(float* __restrict__ ws) {
    int i = blockIdx.x * blockDim.x + threadIdx.x;
    if (i < NCH * 10) ws[i] = 0.0f;
}

// Main: per 16-neighbor tile per wave:
//   h2 = h @ W.T via mfma_f32_16x16x32_bf16 (M=16 nbrs, N=64 ch, K=64)
//   epilogue: radial(n,r) * h2 * monomials -> D[k][10] per-lane accumulators
// Register double-buffer: issue tile t+stride's 7x16B loads before computing
// tile t, so each wave always has one tile of loads in flight.
__global__ __launch_bounds__(256, 2) void ab_main(
    const float* __restrict__ h, const float* __restrict__ rp,
    const float* __restrict__ W, float* __restrict__ ws, int N)
{
    const int lane = threadIdx.x & 63;
    const int wid  = threadIdx.x >> 6;
    const int c = lane & 15;   // A row / C col (k within 16-tile)
    const int g = lane >> 4;   // k-slot group
    const int gwave = blockIdx.x * 4 + wid;
    const int nwave = gridDim.x * 4;

    // B fragments from W: B[j,k] = W[k][j]; lane: col c -> k_local, slots g*8+e -> j
    bf16x8 Bf[4][2];
#pragma unroll
    for (int t = 0; t < 4; ++t)
#pragma unroll
      for (int jb = 0; jb < 2; ++jb) {
        const float* wp = W + (t * 16 + c) * NCH + jb * 32 + g * 8;
        f32x4 w0 = *(const f32x4*)wp;
        f32x4 w1 = *(const f32x4*)(wp + 4);
#pragma unroll
        for (int e = 0; e < 4; ++e) { Bf[t][jb][e] = (__bf16)w0[e]; Bf[t][jb][4 + e] = (__bf16)w1[e]; }
      }

    float D[4][10];
#pragma unroll
    for (int t = 0; t < 4; ++t)
#pragma unroll
      for (int p = 0; p < 10; ++p) D[t][p] = 0.0f;

    const float C0 = 0.632455532033676f; // sqrt(2/5)
    const int numTiles = N >> 4;         // N % 16 == 0 for this problem

    // ---- prefetch buffers (next tile) ----
    f32x4 A0_0, A1_0, A0_1, A1_1, Px, Py, Pz;
    auto issue = [&](int tile) {
        const int base = tile << 4;
        const float* hp = h + (size_t)(base + c) * NCH + g * 8;
        A0_0 = *(const f32x4*)(hp);
        A1_0 = *(const f32x4*)(hp + 4);
        A0_1 = *(const f32x4*)(hp + 32);
        A1_1 = *(const f32x4*)(hp + 36);
        const int a0i = base + g * 4;
        Px = *(const f32x4*)(rp + a0i);
        Py = *(const f32x4*)(rp + N + a0i);
        Pz = *(const f32x4*)(rp + 2 * N + a0i);
    };

    if (gwave < numTiles) issue(gwave);

    for (int tile = gwave; tile < numTiles; tile += nwave) {
        // consume current prefetch into locals, then immediately re-issue
        f32x4 a0_0 = A0_0, a1_0 = A1_0, a0_1 = A0_1, a1_1 = A1_1;
        f32x4 px = Px, py = Py, pz = Pz;
        const int next = tile + nwave;
        issue(next < numTiles ? next : gwave);  // clamp: valid addr, result discarded

        bf16x8 Af[2];
#pragma unroll
        for (int e = 0; e < 4; ++e) {
            Af[0][e] = (__bf16)a0_0[e]; Af[0][4 + e] = (__bf16)a1_0[e];
            Af[1][e] = (__bf16)a0_1[e]; Af[1][4 + e] = (__bf16)a1_1[e];
        }

        f32x4 acc[4];
#pragma unroll
        for (int t = 0; t < 4; ++t) acc[t] = (f32x4){0.f, 0.f, 0.f, 0.f};
#pragma unroll
        for (int jb = 0; jb < 2; ++jb)
#pragma unroll
          for (int t = 0; t < 4; ++t)
            acc[t] = __builtin_amdgcn_mfma_f32_16x16x32_bf16(Af[jb], Bf[t][jb], acc[t], 0, 0, 0);

        // C layout: lane holds rows (neighbors) g*4+i, col k = 16*t + c
#pragma unroll
        for (int i = 0; i < 4; ++i) {
            float x = px[i], y = py[i], z = pz[i];
            float r2 = x * x + y * y + z * z;
            float inv = rsqrtf(r2);
            float nx = x * inv, ny = y * inv, nz = z * inv;
            float rev1 = (r2 * inv) * 0.1f;   // r/10 revolutions per unit n (n*pi*r/5 rad)
            float coef = C0 * inv;            // sqrt(2/5)/r
            float xx = nx * nx, xy = nx * ny, xz = nx * nz;
            float yy = ny * ny, yz = ny * nz, zz = nz * nz;
            float m[10] = { xx * nx, xx * ny, xx * nz, xy * ny, xy * nz,
                            xz * nz, yy * ny, yy * nz, yz * nz, zz * nz };
            float revn = (float)(c + 1) * rev1;
            float rev16 = 16.0f * rev1;
#pragma unroll
            for (int t = 0; t < 4; ++t) {
                float rv = revn - floorf(revn);
                float s = __builtin_amdgcn_sinf(rv);     // sin(2*pi*rv)
                float v = s * coef * acc[t][i];
#pragma unroll
                for (int p = 0; p < 10; ++p) D[t][p] = fmaf(v, m[p], D[t][p]);
                revn += rev16;
            }
        }
    }

    // wave reduce across the 4 groups (same k set, different neighbors)
#pragma unroll
    for (int t = 0; t < 4; ++t)
#pragma unroll
      for (int p = 0; p < 10; ++p) {
        float v = D[t][p];
        v += __shfl_xor(v, 16);
        v += __shfl_xor(v, 32);
        D[t][p] = v;
      }

    __shared__ float Ds[4][NCH * 10];
    if (lane < 16) {
#pragma unroll
        for (int t = 0; t < 4; ++t)
#pragma unroll
          for (int p = 0; p < 10; ++p)
            Ds[wid][(c + 16 * t) * 10 + p] = D[t][p];
    }
    __syncthreads();
    for (int idx = threadIdx.x; idx < NCH * 10; idx += blockDim.x) {
        float s = Ds[0][idx] + Ds[1][idx] + Ds[2][idx] + Ds[3][idx];
        atomicAdd(&ws[idx], s);
    }
}

// expand 10 symmetric monomials -> 27-entry (x,y,z) tensor per channel
__global__ void ab_expand(const float* __restrict__ ws, float* __restrict__ out) {
    const unsigned char tab[27] = { 0,1,2, 1,3,4, 2,4,5,
                                    1,3,4, 3,6,7, 4,7,8,
                                    2,4,5, 4,7,8, 5,8,9 };
    int i = blockIdx.x * blockDim.x + threadIdx.x;
    if (i < NCH * 27) {
        int k = i / 27, cc = i % 27;
        out[i] = ws[k * 10 + tab[cc]];
    }
}

extern "C" void kernel_launch(void* const* d_in, const int* in_sizes, int n_in,
                              void* d_out, int out_size, void* d_ws, size_t ws_size,
                              hipStream_t stream) {
    const float* h  = (const float*)d_in[0];
    const float* rp = (const float*)d_in[1];
    const float* W  = (const float*)d_in[2];
    float* out = (float*)d_out;
    float* ws  = (float*)d_ws;
    const int N = in_sizes[1] / 3;

    ab_zero<<<1, 640, 0, stream>>>(ws);
    ab_main<<<512, 256, 0, stream>>>(h, rp, W, ws, N);
    ab_expand<<<(NCH * 27 + 255) / 256, 256, 0, stream>>>(ws, out);
}